// Round 1
// baseline (891.933 us; speedup 1.0000x reference)
//
#include <hip/hip_runtime.h>
#include <cstdint>

#define NR 8192
#define DIMK 512
#define NE 8192

// dist+argmin kernel tiling
#define BM 128
#define BN 128
#define BK 16
#define ESPLIT 16
#define ERANGE (NE / ESPLIT)   // 512
#define ETILES (ERANGE / BN)   // 4

// proj kernel tiling
#define PM 64
#define PN 64
#define PK 16

// ---------------- Kernel 1: ||E_e||^2 ----------------
__global__ __launch_bounds__(256) void enorm_kernel(const float* __restrict__ E,
                                                    float* __restrict__ enorm) {
    int wave = threadIdx.x >> 6;
    int lane = threadIdx.x & 63;
    int row = blockIdx.x * 4 + wave;
    const float* er = E + (size_t)row * DIMK;
    float s = 0.f;
#pragma unroll
    for (int k = 0; k < DIMK / 64; ++k) {
        float v = er[lane + k * 64];
        s = fmaf(v, v, s);
    }
#pragma unroll
    for (int off = 32; off > 0; off >>= 1) s += __shfl_down(s, off, 64);
    if (lane == 0) enorm[row] = s;
}

// ------- Kernel 2: fused dist matmul + per-split argmin -------
__global__ __launch_bounds__(256) void dist_argmin_kernel(
    const float* __restrict__ X, const float* __restrict__ E,
    const float* __restrict__ enorm,
    float* __restrict__ pval, int* __restrict__ pidx)
{
    __shared__ float xs[BK][BM + 4];
    __shared__ float es[BK][BN + 4];
    __shared__ float rv[BM][17];
    __shared__ int   ri[BM][17];

    const int tid = threadIdx.x;
    const int row0 = blockIdx.y * BM;
    const int e_base = blockIdx.x * ERANGE;

    const int tx = tid & 15;   // 16 col-groups of 8
    const int ty = tid >> 4;   // 16 row-groups of 8

    float minv[8];
    int   mini[8];
#pragma unroll
    for (int i = 0; i < 8; ++i) { minv[i] = 3.4e38f; mini[i] = 0; }

    const int lm = tid >> 1;          // 0..127
    const int lk = (tid & 1) * 8;     // 0 or 8

    for (int et = 0; et < ETILES; ++et) {
        const int e0 = e_base + et * BN;
        float acc[8][8];
#pragma unroll
        for (int i = 0; i < 8; ++i)
#pragma unroll
            for (int j = 0; j < 8; ++j) acc[i][j] = 0.f;

        for (int kt = 0; kt < DIMK / BK; ++kt) {
            const int k0 = kt * BK;
            {
                const float* src = X + (size_t)(row0 + lm) * DIMK + k0 + lk;
                float4 v0 = *(const float4*)(src);
                float4 v1 = *(const float4*)(src + 4);
                xs[lk + 0][lm] = v0.x; xs[lk + 1][lm] = v0.y;
                xs[lk + 2][lm] = v0.z; xs[lk + 3][lm] = v0.w;
                xs[lk + 4][lm] = v1.x; xs[lk + 5][lm] = v1.y;
                xs[lk + 6][lm] = v1.z; xs[lk + 7][lm] = v1.w;
            }
            {
                const float* src = E + (size_t)(e0 + lm) * DIMK + k0 + lk;
                float4 v0 = *(const float4*)(src);
                float4 v1 = *(const float4*)(src + 4);
                es[lk + 0][lm] = v0.x; es[lk + 1][lm] = v0.y;
                es[lk + 2][lm] = v0.z; es[lk + 3][lm] = v0.w;
                es[lk + 4][lm] = v1.x; es[lk + 5][lm] = v1.y;
                es[lk + 6][lm] = v1.z; es[lk + 7][lm] = v1.w;
            }
            __syncthreads();
#pragma unroll
            for (int k = 0; k < BK; ++k) {
                float4 a0 = *(const float4*)&xs[k][ty * 8];
                float4 a1 = *(const float4*)&xs[k][ty * 8 + 4];
                float4 b0 = *(const float4*)&es[k][tx * 8];
                float4 b1 = *(const float4*)&es[k][tx * 8 + 4];
                float av[8] = {a0.x, a0.y, a0.z, a0.w, a1.x, a1.y, a1.z, a1.w};
                float bv[8] = {b0.x, b0.y, b0.z, b0.w, b1.x, b1.y, b1.z, b1.w};
#pragma unroll
                for (int i = 0; i < 8; ++i)
#pragma unroll
                    for (int j = 0; j < 8; ++j)
                        acc[i][j] = fmaf(av[i], bv[j], acc[i][j]);
            }
            __syncthreads();
        }
        // epilogue: s = ||E||^2 - 2 x.E   (||x||^2 dropped: row-constant)
#pragma unroll
        for (int j = 0; j < 8; ++j) {
            const int e = e0 + tx * 8 + j;
            const float en = enorm[e];
#pragma unroll
            for (int i = 0; i < 8; ++i) {
                const float s = fmaf(-2.f, acc[i][j], en);
                if (s < minv[i]) { minv[i] = s; mini[i] = e; }  // strict < keeps first occurrence
            }
        }
    }

    // cross-thread argmin per row (16 tx groups)
#pragma unroll
    for (int i = 0; i < 8; ++i) {
        rv[ty * 8 + i][tx] = minv[i];
        ri[ty * 8 + i][tx] = mini[i];
    }
    __syncthreads();
    if (tid < BM) {
        float bv = rv[tid][0];
        int bi = ri[tid][0];
#pragma unroll
        for (int t = 1; t < 16; ++t) {
            float v = rv[tid][t];
            int ix = ri[tid][t];
            if (v < bv || (v == bv && ix < bi)) { bv = v; bi = ix; }
        }
        const int row = row0 + tid;
        pval[(size_t)row * ESPLIT + blockIdx.x] = bv;
        pidx[(size_t)row * ESPLIT + blockIdx.x] = bi;
    }
}

// ------- Kernel 3: reduce partial argmins across e-splits -------
__global__ __launch_bounds__(256) void reduce_argmin_kernel(
    const float* __restrict__ pval, const int* __restrict__ pidx,
    int* __restrict__ ind)
{
    int r = blockIdx.x * blockDim.x + threadIdx.x;
    if (r >= NR) return;
    float bv = pval[(size_t)r * ESPLIT];
    int bi = pidx[(size_t)r * ESPLIT];
#pragma unroll
    for (int s = 1; s < ESPLIT; ++s) {
        float v = pval[(size_t)r * ESPLIT + s];
        int ix = pidx[(size_t)r * ESPLIT + s];
        if (v < bv || (v == bv && ix < bi)) { bv = v; bi = ix; }
    }
    ind[r] = bi;
}

// ------- Kernel 4: out = x + (x - E[ind]) @ W^T + b -------
__global__ __launch_bounds__(256) void proj_kernel(
    const float* __restrict__ X, const float* __restrict__ E,
    const int* __restrict__ ind,
    const float* __restrict__ W, const float* __restrict__ Bv,
    float* __restrict__ Out)
{
    __shared__ float as_[PK][PM + 4];
    __shared__ float bs[PK][PN + 4];
    __shared__ int inds[PM];

    const int tid = threadIdx.x;
    const int row0 = blockIdx.y * PM;
    const int col0 = blockIdx.x * PN;

    if (tid < PM) inds[tid] = ind[row0 + tid];
    __syncthreads();

    const int tx = tid & 15;
    const int ty = tid >> 4;

    float acc[4][4];
#pragma unroll
    for (int i = 0; i < 4; ++i)
#pragma unroll
        for (int j = 0; j < 4; ++j) acc[i][j] = 0.f;

    const int lm = tid >> 2;          // 0..63
    const int lk = (tid & 3) * 4;     // 0,4,8,12

    for (int kt = 0; kt < DIMK / PK; ++kt) {
        const int k0 = kt * PK;
        {
            float4 xv = *(const float4*)(X + (size_t)(row0 + lm) * DIMK + k0 + lk);
            float4 qv = *(const float4*)(E + (size_t)inds[lm] * DIMK + k0 + lk);
            as_[lk + 0][lm] = xv.x - qv.x;
            as_[lk + 1][lm] = xv.y - qv.y;
            as_[lk + 2][lm] = xv.z - qv.z;
            as_[lk + 3][lm] = xv.w - qv.w;
        }
        {
            float4 wv = *(const float4*)(W + (size_t)(col0 + lm) * DIMK + k0 + lk);
            bs[lk + 0][lm] = wv.x; bs[lk + 1][lm] = wv.y;
            bs[lk + 2][lm] = wv.z; bs[lk + 3][lm] = wv.w;
        }
        __syncthreads();
#pragma unroll
        for (int k = 0; k < PK; ++k) {
            float4 a = *(const float4*)&as_[k][ty * 4];
            float4 b = *(const float4*)&bs[k][tx * 4];
            float av[4] = {a.x, a.y, a.z, a.w};
            float bvv[4] = {b.x, b.y, b.z, b.w};
#pragma unroll
            for (int i = 0; i < 4; ++i)
#pragma unroll
                for (int j = 0; j < 4; ++j)
                    acc[i][j] = fmaf(av[i], bvv[j], acc[i][j]);
        }
        __syncthreads();
    }

#pragma unroll
    for (int j = 0; j < 4; ++j) {
        const int col = col0 + tx * 4 + j;
        const float bias = Bv[col];
#pragma unroll
        for (int i = 0; i < 4; ++i) {
            const int row = row0 + ty * 4 + i;
            Out[(size_t)row * DIMK + col] =
                X[(size_t)row * DIMK + col] + acc[i][j] + bias;
        }
    }
}

extern "C" void kernel_launch(void* const* d_in, const int* in_sizes, int n_in,
                              void* d_out, int out_size, void* d_ws, size_t ws_size,
                              hipStream_t stream) {
    const float* X = (const float*)d_in[0];
    const float* E = (const float*)d_in[1];
    const float* W = (const float*)d_in[2];
    const float* B = (const float*)d_in[3];
    float* out = (float*)d_out;

    float* enorm = (float*)d_ws;                       // NE floats
    float* pval = enorm + NE;                          // NR*ESPLIT floats
    int* pidx = (int*)(pval + (size_t)NR * ESPLIT);    // NR*ESPLIT ints
    int* ind = pidx + (size_t)NR * ESPLIT;             // NR ints

    hipLaunchKernelGGL(enorm_kernel, dim3(NE / 4), dim3(256), 0, stream, E, enorm);
    hipLaunchKernelGGL(dist_argmin_kernel, dim3(ESPLIT, NR / BM), dim3(256), 0, stream,
                       X, E, enorm, pval, pidx);
    hipLaunchKernelGGL(reduce_argmin_kernel, dim3(NR / 256), dim3(256), 0, stream,
                       pval, pidx, ind);
    hipLaunchKernelGGL(proj_kernel, dim3(DIMK / PN, NR / PM), dim3(256), 0, stream,
                       X, E, ind, W, B, out);
}